// Round 5
// baseline (856.819 us; speedup 1.0000x reference)
//
#include <hip/hip_runtime.h>
#include <math.h>

#define BATCH 2
#define SEQ 2048
#define DM 1024
#define NH 16
#define DH 64
#define TOPKN 1024
#define MROWS (BATCH * SEQ)  // 4096

typedef float f32x4 __attribute__((ext_vector_type(4)));
typedef short s16x8 __attribute__((ext_vector_type(8)));
typedef short s16x4 __attribute__((ext_vector_type(4)));

// PV MFMA: 16x16x16 bf16 (B-fragment k-chunk of 4 matches swapped-QK^T acc layout)
#if __has_builtin(__builtin_amdgcn_mfma_f32_16x16x16_bf16)
#define MFMA1616(acc, a, b) acc = __builtin_amdgcn_mfma_f32_16x16x16_bf16(a, b, acc, 0, 0, 0)
#define MFMA1616_FENCE()
#elif __has_builtin(__builtin_amdgcn_mfma_f32_16x16x16bf16_1k)
#define MFMA1616(acc, a, b) acc = __builtin_amdgcn_mfma_f32_16x16x16bf16_1k(a, b, acc, 0, 0, 0)
#define MFMA1616_FENCE()
#else
#define MFMA1616(acc, a, b) \
  asm volatile("v_mfma_f32_16x16x16_bf16 %0, %1, %2, %0" : "+v"(acc) : "v"(a), "v"(b))
#define MFMA1616_FENCE() asm volatile("s_nop 7\ns_nop 7")
#endif

__device__ __forceinline__ unsigned short f2bf(float x) {
  unsigned u = __float_as_uint(x);
  return (unsigned short)((u + 0x7FFFu + ((u >> 16) & 1u)) >> 16);
}
__device__ __forceinline__ unsigned packHL(float x) {
  unsigned h = f2bf(x);
  float r = x - __uint_as_float(h << 16);
  unsigned l = f2bf(r);
  return h | (l << 16);
}

// ---------------- W pre-convert: f32 -> hi/lo bf16 slabs ----------------
__global__ __launch_bounds__(256) void convW(const float* __restrict__ W,
                                             unsigned short* __restrict__ Whi,
                                             unsigned short* __restrict__ Wlo) {
  int i = (blockIdx.x * 256 + threadIdx.x) * 4;
  float4 x = *(const float4*)&W[i];
  float xs[4] = {x.x, x.y, x.z, x.w};
  union { s16x4 v; unsigned short s[4]; } hu, lu;
#pragma unroll
  for (int e = 0; e < 4; ++e) {
    unsigned short hb = f2bf(xs[e]);
    hu.s[e] = hb;
    lu.s[e] = f2bf(xs[e] - __uint_as_float((unsigned)hb << 16));
  }
  *(s16x4*)&Whi[i] = hu.v;
  *(s16x4*)&Wlo[i] = lu.v;
}

// ---------------- MFMA GEMM: C[4096,1024] = A @ W^T + bias ----------------
// 3-term split-bf16. BM=128, BN=64, BK=64; 4 waves (2x2), wave-tile 64x32.
// ASRC: 0 = f32 A, 1 = packed u32 (hi|lo<<16).
// MODE: 0 f32 out, 1 packed Q(*0.125), 2 Khi/Klo, 3 Vt transposed.
template <int ASRC, int MODE>
__global__ __launch_bounds__(256) void gemm_mfma(
    const void* __restrict__ Asrc, const unsigned short* __restrict__ Whi,
    const unsigned short* __restrict__ Wlo, const float* __restrict__ bias,
    void* __restrict__ out0, void* __restrict__ out1) {
  __shared__ unsigned short Ah[128][64], Al[128][64];
  __shared__ unsigned short Bh[64][64], Bl[64][64];

  const int f = blockIdx.x;              // 512 blocks
  const int xcd = f & 7, s = f >> 3;
  const int bm = xcd * 4 + (s >> 4);
  const int bn = s & 15;
  const int m0g = bm * 128, n0g = bn * 64;
  const int t = threadIdx.x, w = t >> 6, lane = t & 63;
  const int g = lane >> 4, c = lane & 15;
  const int wm = w >> 1, wn = w & 1;

  f32x4 acc[4][2];
#pragma unroll
  for (int i = 0; i < 4; ++i)
#pragma unroll
    for (int j = 0; j < 2; ++j) acc[i][j] = (f32x4){0.f, 0.f, 0.f, 0.f};

#pragma unroll 1
  for (int k0 = 0; k0 < 1024; k0 += 64) {
#pragma unroll
    for (int i = 0; i < 4; ++i) {
      int oid = t * 4 + i;
      int r = oid >> 3, j = oid & 7;
      union { s16x8 v; unsigned short sh[8]; } hu, lu;
      if (ASRC == 0) {
        const float* src = (const float*)Asrc + (size_t)(m0g + r) * 1024 + k0 + j * 8;
        float4 x0 = *(const float4*)src, x1 = *(const float4*)(src + 4);
        float xs[8] = {x0.x, x0.y, x0.z, x0.w, x1.x, x1.y, x1.z, x1.w};
#pragma unroll
        for (int e = 0; e < 8; ++e) {
          unsigned u = __float_as_uint(xs[e]);
          hu.sh[e] = (unsigned short)(u >> 16);
          lu.sh[e] = f2bf(xs[e] - __uint_as_float(u & 0xFFFF0000u));
        }
      } else {
        const unsigned* src = (const unsigned*)Asrc + (size_t)(m0g + r) * 1024 + k0 + j * 8;
        uint4 u0 = *(const uint4*)src, u1 = *(const uint4*)(src + 4);
        unsigned us[8] = {u0.x, u0.y, u0.z, u0.w, u1.x, u1.y, u1.z, u1.w};
#pragma unroll
        for (int e = 0; e < 8; ++e) {
          hu.sh[e] = (unsigned short)(us[e] & 0xFFFFu);
          lu.sh[e] = (unsigned short)(us[e] >> 16);
        }
      }
      int od = (j ^ (r & 7)) * 8;
      *(s16x8*)&Ah[r][od] = hu.v;
      *(s16x8*)&Al[r][od] = lu.v;
    }
#pragma unroll
    for (int i = 0; i < 4; ++i) {
      int oid = t * 4 + i;
      int pl = oid >> 9, idx = oid & 511, r = idx >> 3, j = idx & 7;
      const unsigned short* src = (pl ? Wlo : Whi) + (size_t)(n0g + r) * 1024 + k0 + j * 8;
      uint4 d = *(const uint4*)src;
      int od = (j ^ (r & 7)) * 8;
      if (pl) *(uint4*)&Bl[r][od] = d; else *(uint4*)&Bh[r][od] = d;
    }
    __syncthreads();
#pragma unroll
    for (int k2 = 0; k2 < 2; ++k2) {
      s16x8 ah[4], al4[4], bh[2], bl[2];
      int ob = ((k2 * 4 + g) ^ (c & 7)) * 8;
#pragma unroll
      for (int i = 0; i < 4; ++i) {
        int r = wm * 64 + i * 16 + c;
        ah[i] = *(const s16x8*)&Ah[r][ob];
        al4[i] = *(const s16x8*)&Al[r][ob];
      }
#pragma unroll
      for (int j = 0; j < 2; ++j) {
        int r = wn * 32 + j * 16 + c;
        bh[j] = *(const s16x8*)&Bh[r][ob];
        bl[j] = *(const s16x8*)&Bl[r][ob];
      }
#pragma unroll
      for (int i = 0; i < 4; ++i)
#pragma unroll
        for (int j = 0; j < 2; ++j) {
          acc[i][j] = __builtin_amdgcn_mfma_f32_16x16x32_bf16(ah[i], bh[j], acc[i][j], 0, 0, 0);
          acc[i][j] = __builtin_amdgcn_mfma_f32_16x16x32_bf16(ah[i], bl[j], acc[i][j], 0, 0, 0);
          acc[i][j] = __builtin_amdgcn_mfma_f32_16x16x32_bf16(al4[i], bh[j], acc[i][j], 0, 0, 0);
        }
    }
    __syncthreads();
  }

#pragma unroll
  for (int j = 0; j < 2; ++j) {
    const int col = n0g + wn * 32 + j * 16 + c;
    const float bj = bias[col];
#pragma unroll
    for (int i = 0; i < 4; ++i) {
      const int row0 = m0g + wm * 64 + i * 16 + g * 4;
      if (MODE == 0) {
        float* O = (float*)out0;
#pragma unroll
        for (int rr = 0; rr < 4; ++rr)
          O[(size_t)(row0 + rr) * 1024 + col] = acc[i][j][rr] + bj;
      } else if (MODE == 1) {
        unsigned* Q = (unsigned*)out0;
#pragma unroll
        for (int rr = 0; rr < 4; ++rr)
          Q[(size_t)(row0 + rr) * 1024 + col] = packHL((acc[i][j][rr] + bj) * 0.125f);
      } else if (MODE == 2) {
        unsigned short* Khi = (unsigned short*)out0;
        unsigned short* Klo = (unsigned short*)out1;
#pragma unroll
        for (int rr = 0; rr < 4; ++rr) {
          float x = acc[i][j][rr] + bj;
          unsigned short hb = f2bf(x);
          Khi[(size_t)(row0 + rr) * 1024 + col] = hb;
          Klo[(size_t)(row0 + rr) * 1024 + col] = f2bf(x - __uint_as_float((unsigned)hb << 16));
        }
      } else {
        unsigned short* Vt = (unsigned short*)out0;
        int b = row0 >> 11, l0 = row0 & (SEQ - 1);
        int h = col >> 6, dh = col & 63;
        union { s16x4 v; unsigned short sh[4]; } vv;
#pragma unroll
        for (int rr = 0; rr < 4; ++rr) vv.sh[rr] = f2bf(acc[i][j][rr] + bj);
        *(s16x4*)&Vt[(((size_t)b * NH + h) * DH + dh) * SEQ + l0] = vv.v;
      }
    }
  }
}

// ---------------- fused prob-sparse attention (swapped-MFMA, reg-resident P) ----
// 4096 WGs x 256 thr. Swapped QK^T: accs[tt][r] = S[q = lane&15][k = w*512+tt*16+(lane>>4)*4+r].
// Bisection (14 iters, [vmax-4, vmax]) -> threshold; exp in-place; PV via
// 16x16x16 MFMA consuming P directly from registers (B-frag layout match).
__global__ __launch_bounds__(256, 2) void attn_mfma(
    const unsigned* __restrict__ QHL, const unsigned short* __restrict__ Khi,
    const unsigned short* __restrict__ Klo, const unsigned short* __restrict__ Vt,
    unsigned* __restrict__ CtxP) {
  __shared__ __align__(16) float smax[16][4];
  __shared__ __align__(16) unsigned scnt[2][16][4];
  __shared__ __align__(16) float szum[16][4];
  __shared__ __align__(16) float ctxp[4][16][72];   // pad 72: <=4-way banks

  int wg = blockIdx.x;
  wg = (wg & 7) * 512 + (wg >> 3);                  // XCD-contiguous (b,h) groups
  const int bh = wg >> 7, qt = wg & 127;
  const int b = bh >> 4, h = bh & 15;
  const int q0 = qt * 16;
  const int t = threadIdx.x, w = t >> 6, lane = t & 63;
  const int g = lane >> 4, c = lane & 15;
  const size_t rowb = (size_t)b * SEQ;

  // ---- Q B-fragments (packed u32, pre-scaled by 1/8) ----
  s16x8 qhi[2], qlo[2];
  {
    const unsigned* qp = QHL + (rowb + q0 + c) * DM + h * DH + g * 8;
#pragma unroll
    for (int ds = 0; ds < 2; ++ds) {
      unsigned uw[8];
      *(uint4*)&uw[0] = *(const uint4*)(qp + ds * 32);
      *(uint4*)&uw[4] = *(const uint4*)(qp + ds * 32 + 4);
      union { s16x8 v; unsigned u[4]; } hi_, lo_;
#pragma unroll
      for (int p = 0; p < 4; ++p) {
        hi_.u[p] = (uw[2 * p] & 0xFFFFu) | (uw[2 * p + 1] << 16);
        lo_.u[p] = (uw[2 * p] >> 16) | (uw[2 * p + 1] & 0xFFFF0000u);
      }
      qhi[ds] = hi_.v; qlo[ds] = lo_.v;
    }
  }

  // ---- swapped QK^T: S^T = Khi*Qhi + Klo*Qhi + Khi*Qlo ----
  f32x4 accs[32];
#pragma unroll
  for (int i = 0; i < 32; ++i) accs[i] = (f32x4){0.f, 0.f, 0.f, 0.f};
  {
    const size_t kcol = (size_t)h * DH + g * 8;
#pragma unroll
    for (int tt = 0; tt < 32; ++tt) {
      const size_t krow = (rowb + w * 512 + tt * 16 + c) * DM + kcol;
      s16x8 kh0 = *(const s16x8*)(Khi + krow);
      s16x8 kh1 = *(const s16x8*)(Khi + krow + 32);
      s16x8 kl0 = *(const s16x8*)(Klo + krow);
      s16x8 kl1 = *(const s16x8*)(Klo + krow + 32);
      accs[tt] = __builtin_amdgcn_mfma_f32_16x16x32_bf16(kh0, qhi[0], accs[tt], 0, 0, 0);
      accs[tt] = __builtin_amdgcn_mfma_f32_16x16x32_bf16(kh1, qhi[1], accs[tt], 0, 0, 0);
      accs[tt] = __builtin_amdgcn_mfma_f32_16x16x32_bf16(kl0, qhi[0], accs[tt], 0, 0, 0);
      accs[tt] = __builtin_amdgcn_mfma_f32_16x16x32_bf16(kl1, qhi[1], accs[tt], 0, 0, 0);
      accs[tt] = __builtin_amdgcn_mfma_f32_16x16x32_bf16(kh0, qlo[0], accs[tt], 0, 0, 0);
      accs[tt] = __builtin_amdgcn_mfma_f32_16x16x32_bf16(kh1, qlo[1], accs[tt], 0, 0, 0);
    }
  }

  // ---- row max (row = c), thread-local + shfl over g + LDS over waves ----
  float vm;
  {
    float m = accs[0][0];
#pragma unroll
    for (int tt = 0; tt < 32; ++tt)
#pragma unroll
      for (int r = 0; r < 4; ++r) m = fmaxf(m, accs[tt][r]);
    m = fmaxf(m, __shfl_xor(m, 16));
    m = fmaxf(m, __shfl_xor(m, 32));
    if (lane < 16) smax[c][w] = m;
    __syncthreads();
    float4 m4 = *(float4*)&smax[c][0];
    vm = fmaxf(fmaxf(m4.x, m4.y), fmaxf(m4.z, m4.w));
  }

  // ---- threshold: 14-iter float bisection on [vmax-4, vmax] ----
  float blo = vm - 4.0f, bhi = vm;
#pragma unroll 1
  for (int it = 0; it < 14; ++it) {
    const int par = it & 1;
    const float mid = 0.5f * (blo + bhi);
    int cnt = 0;
#pragma unroll
    for (int tt = 0; tt < 32; ++tt)
#pragma unroll
      for (int r = 0; r < 4; ++r) cnt += (accs[tt][r] >= mid) ? 1 : 0;
    cnt += __shfl_xor(cnt, 16);
    cnt += __shfl_xor(cnt, 32);
    if (lane < 16) scnt[par][c][w] = (unsigned)cnt;
    __syncthreads();
    uint4 cc = *(uint4*)&scnt[par][c][0];
    int tot = (int)(cc.x + cc.y + cc.z + cc.w);
    bool ge = tot >= TOPKN;
    blo = ge ? mid : blo;
    bhi = ge ? bhi : mid;
  }

  // ---- exp in-place + Z ----
  float rinv;
  {
    const float L2E = 1.44269504f;
    const float mh = vm * L2E;
    float z = 0.f;
#pragma unroll
    for (int tt = 0; tt < 32; ++tt)
#pragma unroll
      for (int r = 0; r < 4; ++r) {
        float s = accs[tt][r];
        float e = (s >= blo) ? exp2f(fmaf(s, L2E, -mh)) : 0.f;
        z += e;
        accs[tt][r] = e;
      }
    z += __shfl_xor(z, 16);
    z += __shfl_xor(z, 32);
    if (lane < 16) szum[c][w] = z;
    __syncthreads();
    float4 z4 = *(float4*)&szum[c][0];
    rinv = 1.f / (z4.x + z4.y + z4.z + z4.w);
  }

  // ---- PV: 16x16x16 MFMA, P from registers (B), V^T from global (A) ----
  f32x4 opv[4];
#pragma unroll
  for (int j = 0; j < 4; ++j) opv[j] = (f32x4){0.f, 0.f, 0.f, 0.f};
  {
    const unsigned short* vb0 = Vt + ((size_t)bh * DH + c) * SEQ + w * 512 + g * 4;
#pragma unroll 2
    for (int kt = 0; kt < 32; ++kt) {
      union { s16x4 v; unsigned u[2]; } pb;
      unsigned u0 = __float_as_uint(accs[kt][0]);
      unsigned u1 = __float_as_uint(accs[kt][1]);
      unsigned u2 = __float_as_uint(accs[kt][2]);
      unsigned u3 = __float_as_uint(accs[kt][3]);
      pb.u[0] = ((u0 + 0x8000u) >> 16) | ((u1 + 0x8000u) & 0xFFFF0000u);
      pb.u[1] = ((u2 + 0x8000u) >> 16) | ((u3 + 0x8000u) & 0xFFFF0000u);
#pragma unroll
      for (int j = 0; j < 4; ++j) {
        s16x4 va = *(const s16x4*)(vb0 + (size_t)j * 16 * SEQ + kt * 16);
        MFMA1616(opv[j], va, pb.v);
      }
    }
    MFMA1616_FENCE();
  }

  // ---- cross-wave reduce + scale + packed store ----
#pragma unroll
  for (int j = 0; j < 4; ++j)
    *(f32x4*)&ctxp[w][c][j * 16 + g * 4] = opv[j];
  __syncthreads();
  {
    f32x4 s0 = *(const f32x4*)&ctxp[0][c][w * 16 + g * 4];
    f32x4 s1 = *(const f32x4*)&ctxp[1][c][w * 16 + g * 4];
    f32x4 s2 = *(const f32x4*)&ctxp[2][c][w * 16 + g * 4];
    f32x4 s3 = *(const f32x4*)&ctxp[3][c][w * 16 + g * 4];
    f32x4 ssum = (s0 + s1) + (s2 + s3);
    unsigned ov[4];
    ov[0] = packHL(ssum[0] * rinv);
    ov[1] = packHL(ssum[1] * rinv);
    ov[2] = packHL(ssum[2] * rinv);
    ov[3] = packHL(ssum[3] * rinv);
    *(uint4*)&CtxP[(rowb + q0 + c) * DM + h * DH + w * 16 + g * 4] = *(uint4*)&ov[0];
  }
}

extern "C" void kernel_launch(void* const* d_in, const int* in_sizes, int n_in,
                              void* d_out, int out_size, void* d_ws, size_t ws_size,
                              hipStream_t stream) {
  const float* q  = (const float*)d_in[0];
  const float* k  = (const float*)d_in[1];
  const float* v  = (const float*)d_in[2];
  const float* Wq = (const float*)d_in[3];
  const float* bq = (const float*)d_in[4];
  const float* Wk = (const float*)d_in[5];
  const float* bk = (const float*)d_in[6];
  const float* Wv = (const float*)d_in[7];
  const float* bv = (const float*)d_in[8];
  const float* Wo = (const float*)d_in[9];
  const float* bo = (const float*)d_in[10];
  float* out = (float*)d_out;

  char* ws = (char*)d_ws;
  unsigned* QHL       = (unsigned*)ws;                        // 16 MiB (packed hi|lo)
  unsigned short* Khi = (unsigned short*)(ws + (16u << 20));  // 8 MiB
  unsigned short* Klo = (unsigned short*)(ws + (24u << 20));  // 8 MiB
  unsigned short* Vt  = (unsigned short*)(ws + (32u << 20));  // 8 MiB
  unsigned short* Whi = (unsigned short*)(ws + (40u << 20));  // 2 MiB (reused)
  unsigned short* Wlo = (unsigned short*)(ws + (42u << 20));  // 2 MiB (reused)

  convW<<<1024, 256, 0, stream>>>(Wq, Whi, Wlo);
  gemm_mfma<0, 1><<<512, 256, 0, stream>>>(q, Whi, Wlo, bq, QHL, nullptr);
  convW<<<1024, 256, 0, stream>>>(Wk, Whi, Wlo);
  gemm_mfma<0, 2><<<512, 256, 0, stream>>>(k, Whi, Wlo, bk, Khi, Klo);
  convW<<<1024, 256, 0, stream>>>(Wv, Whi, Wlo);
  gemm_mfma<0, 3><<<512, 256, 0, stream>>>(v, Whi, Wlo, bv, Vt, nullptr);
  attn_mfma<<<BATCH * NH * (SEQ / 16), 256, 0, stream>>>(QHL, Khi, Klo, Vt, QHL);
  convW<<<1024, 256, 0, stream>>>(Wo, Whi, Wlo);
  gemm_mfma<1, 0><<<512, 256, 0, stream>>>(QHL, Whi, Wlo, bo, out, nullptr);
}

// Round 6
// 793.718 us; speedup vs baseline: 1.0795x; 1.0795x over previous
//
#include <hip/hip_runtime.h>
#include <math.h>

#define BATCH 2
#define SEQ 2048
#define DM 1024
#define NH 16
#define DH 64
#define TOPKN 1024
#define MROWS (BATCH * SEQ)  // 4096

typedef float f32x4 __attribute__((ext_vector_type(4)));
typedef short s16x8 __attribute__((ext_vector_type(8)));
typedef short s16x4 __attribute__((ext_vector_type(4)));

// PV MFMA: 16x16x16 bf16 (B-fragment k-chunk of 4 matches swapped-QK^T acc layout)
#if __has_builtin(__builtin_amdgcn_mfma_f32_16x16x16_bf16)
#define MFMA1616(acc, a, b) acc = __builtin_amdgcn_mfma_f32_16x16x16_bf16(a, b, acc, 0, 0, 0)
#define MFMA1616_FENCE()
#elif __has_builtin(__builtin_amdgcn_mfma_f32_16x16x16bf16_1k)
#define MFMA1616(acc, a, b) acc = __builtin_amdgcn_mfma_f32_16x16x16bf16_1k(a, b, acc, 0, 0, 0)
#define MFMA1616_FENCE()
#else
#define MFMA1616(acc, a, b) \
  asm volatile("v_mfma_f32_16x16x16_bf16 %0, %1, %2, %0" : "+v"(acc) : "v"(a), "v"(b))
#define MFMA1616_FENCE() asm volatile("s_nop 7\ns_nop 7")
#endif

__device__ __forceinline__ unsigned short f2bf(float x) {
  unsigned u = __float_as_uint(x);
  return (unsigned short)((u + 0x7FFFu + ((u >> 16) & 1u)) >> 16);
}
__device__ __forceinline__ unsigned packHL(float x) {
  unsigned h = f2bf(x);
  float r = x - __uint_as_float(h << 16);
  unsigned l = f2bf(r);
  return h | (l << 16);
}

// ---------------- W pre-convert: f32 -> hi/lo bf16 slabs ----------------
__global__ __launch_bounds__(256) void convW(const float* __restrict__ W,
                                             unsigned short* __restrict__ Whi,
                                             unsigned short* __restrict__ Wlo) {
  int i = (blockIdx.x * 256 + threadIdx.x) * 4;
  float4 x = *(const float4*)&W[i];
  float xs[4] = {x.x, x.y, x.z, x.w};
  union { s16x4 v; unsigned short s[4]; } hu, lu;
#pragma unroll
  for (int e = 0; e < 4; ++e) {
    unsigned short hb = f2bf(xs[e]);
    hu.s[e] = hb;
    lu.s[e] = f2bf(xs[e] - __uint_as_float((unsigned)hb << 16));
  }
  *(s16x4*)&Whi[i] = hu.v;
  *(s16x4*)&Wlo[i] = lu.v;
}

// ---------------- MFMA GEMM: C[4096,1024] = A @ W^T + bias ----------------
// 3-term split-bf16. BM=128, BN=64, BK=64; 4 waves (2x2), wave-tile 64x32.
// ASRC: 0 = f32 A, 1 = packed u32 (hi|lo<<16).
// MODE: 0 f32 out, 1 packed Q(*0.125), 2 Khi/Klo, 3 Vt transposed.
template <int ASRC, int MODE>
__global__ __launch_bounds__(256) void gemm_mfma(
    const void* __restrict__ Asrc, const unsigned short* __restrict__ Whi,
    const unsigned short* __restrict__ Wlo, const float* __restrict__ bias,
    void* __restrict__ out0, void* __restrict__ out1) {
  __shared__ unsigned short Ah[128][64], Al[128][64];
  __shared__ unsigned short Bh[64][64], Bl[64][64];

  const int f = blockIdx.x;              // 512 blocks
  const int xcd = f & 7, s = f >> 3;
  const int bm = xcd * 4 + (s >> 4);
  const int bn = s & 15;
  const int m0g = bm * 128, n0g = bn * 64;
  const int t = threadIdx.x, w = t >> 6, lane = t & 63;
  const int g = lane >> 4, c = lane & 15;
  const int wm = w >> 1, wn = w & 1;

  f32x4 acc[4][2];
#pragma unroll
  for (int i = 0; i < 4; ++i)
#pragma unroll
    for (int j = 0; j < 2; ++j) acc[i][j] = (f32x4){0.f, 0.f, 0.f, 0.f};

#pragma unroll 1
  for (int k0 = 0; k0 < 1024; k0 += 64) {
#pragma unroll
    for (int i = 0; i < 4; ++i) {
      int oid = t * 4 + i;
      int r = oid >> 3, j = oid & 7;
      union { s16x8 v; unsigned short sh[8]; } hu, lu;
      if (ASRC == 0) {
        const float* src = (const float*)Asrc + (size_t)(m0g + r) * 1024 + k0 + j * 8;
        float4 x0 = *(const float4*)src, x1 = *(const float4*)(src + 4);
        float xs[8] = {x0.x, x0.y, x0.z, x0.w, x1.x, x1.y, x1.z, x1.w};
#pragma unroll
        for (int e = 0; e < 8; ++e) {
          unsigned u = __float_as_uint(xs[e]);
          hu.sh[e] = (unsigned short)(u >> 16);
          lu.sh[e] = f2bf(xs[e] - __uint_as_float(u & 0xFFFF0000u));
        }
      } else {
        const unsigned* src = (const unsigned*)Asrc + (size_t)(m0g + r) * 1024 + k0 + j * 8;
        uint4 u0 = *(const uint4*)src, u1 = *(const uint4*)(src + 4);
        unsigned us[8] = {u0.x, u0.y, u0.z, u0.w, u1.x, u1.y, u1.z, u1.w};
#pragma unroll
        for (int e = 0; e < 8; ++e) {
          hu.sh[e] = (unsigned short)(us[e] & 0xFFFFu);
          lu.sh[e] = (unsigned short)(us[e] >> 16);
        }
      }
      int od = (j ^ (r & 7)) * 8;
      *(s16x8*)&Ah[r][od] = hu.v;
      *(s16x8*)&Al[r][od] = lu.v;
    }
#pragma unroll
    for (int i = 0; i < 4; ++i) {
      int oid = t * 4 + i;
      int pl = oid >> 9, idx = oid & 511, r = idx >> 3, j = idx & 7;
      const unsigned short* src = (pl ? Wlo : Whi) + (size_t)(n0g + r) * 1024 + k0 + j * 8;
      uint4 d = *(const uint4*)src;
      int od = (j ^ (r & 7)) * 8;
      if (pl) *(uint4*)&Bl[r][od] = d; else *(uint4*)&Bh[r][od] = d;
    }
    __syncthreads();
#pragma unroll
    for (int k2 = 0; k2 < 2; ++k2) {
      s16x8 ah[4], al4[4], bh[2], bl[2];
      int ob = ((k2 * 4 + g) ^ (c & 7)) * 8;
#pragma unroll
      for (int i = 0; i < 4; ++i) {
        int r = wm * 64 + i * 16 + c;
        ah[i] = *(const s16x8*)&Ah[r][ob];
        al4[i] = *(const s16x8*)&Al[r][ob];
      }
#pragma unroll
      for (int j = 0; j < 2; ++j) {
        int r = wn * 32 + j * 16 + c;
        bh[j] = *(const s16x8*)&Bh[r][ob];
        bl[j] = *(const s16x8*)&Bl[r][ob];
      }
#pragma unroll
      for (int i = 0; i < 4; ++i)
#pragma unroll
        for (int j = 0; j < 2; ++j) {
          acc[i][j] = __builtin_amdgcn_mfma_f32_16x16x32_bf16(ah[i], bh[j], acc[i][j], 0, 0, 0);
          acc[i][j] = __builtin_amdgcn_mfma_f32_16x16x32_bf16(ah[i], bl[j], acc[i][j], 0, 0, 0);
          acc[i][j] = __builtin_amdgcn_mfma_f32_16x16x32_bf16(al4[i], bh[j], acc[i][j], 0, 0, 0);
        }
    }
    __syncthreads();
  }

#pragma unroll
  for (int j = 0; j < 2; ++j) {
    const int col = n0g + wn * 32 + j * 16 + c;
    const float bj = bias[col];
#pragma unroll
    for (int i = 0; i < 4; ++i) {
      const int row0 = m0g + wm * 64 + i * 16 + g * 4;
      if (MODE == 0) {
        float* O = (float*)out0;
#pragma unroll
        for (int rr = 0; rr < 4; ++rr)
          O[(size_t)(row0 + rr) * 1024 + col] = acc[i][j][rr] + bj;
      } else if (MODE == 1) {
        unsigned* Q = (unsigned*)out0;
#pragma unroll
        for (int rr = 0; rr < 4; ++rr)
          Q[(size_t)(row0 + rr) * 1024 + col] = packHL((acc[i][j][rr] + bj) * 0.125f);
      } else if (MODE == 2) {
        unsigned short* Khi = (unsigned short*)out0;
        unsigned short* Klo = (unsigned short*)out1;
#pragma unroll
        for (int rr = 0; rr < 4; ++rr) {
          float x = acc[i][j][rr] + bj;
          unsigned short hb = f2bf(x);
          Khi[(size_t)(row0 + rr) * 1024 + col] = hb;
          Klo[(size_t)(row0 + rr) * 1024 + col] = f2bf(x - __uint_as_float((unsigned)hb << 16));
        }
      } else {
        unsigned short* Vt = (unsigned short*)out0;
        int b = row0 >> 11, l0 = row0 & (SEQ - 1);
        int h = col >> 6, dh = col & 63;
        union { s16x4 v; unsigned short sh[4]; } vv;
#pragma unroll
        for (int rr = 0; rr < 4; ++rr) vv.sh[rr] = f2bf(acc[i][j][rr] + bj);
        *(s16x4*)&Vt[(((size_t)b * NH + h) * DH + dh) * SEQ + l0] = vv.v;
      }
    }
  }
}

// ---------------- fused prob-sparse attention (swapped-MFMA, reg-resident P) ----
// 4096 WGs x 256 thr. Swapped QK^T: accs[tt][r] = S[q = lane&15][k = w*512+tt*16+(lane>>4)*4+r].
// Bisection (14 iters, [vmax-4, vmax]) -> threshold; exp in-place; PV via
// 16x16x16 MFMA consuming P directly from registers (B-frag layout match).
// NOTE: every accs[] access must be compile-time-indexed (rule #20) -- the
// round-5 "#pragma unroll 2" PV loop demoted accs to scratch (1.1 GB writes).
__global__ __launch_bounds__(256, 2) void attn_mfma(
    const unsigned* __restrict__ QHL, const unsigned short* __restrict__ Khi,
    const unsigned short* __restrict__ Klo, const unsigned short* __restrict__ Vt,
    unsigned* __restrict__ CtxP) {
  __shared__ __align__(16) float smax[16][4];
  __shared__ __align__(16) unsigned scnt[2][16][4];
  __shared__ __align__(16) float szum[16][4];
  __shared__ __align__(16) float ctxp[4][16][72];   // pad 72: <=4-way banks

  int wg = blockIdx.x;
  wg = (wg & 7) * 512 + (wg >> 3);                  // XCD-contiguous (b,h) groups
  const int bh = wg >> 7, qt = wg & 127;
  const int b = bh >> 4, h = bh & 15;
  const int q0 = qt * 16;
  const int t = threadIdx.x, w = t >> 6, lane = t & 63;
  const int g = lane >> 4, c = lane & 15;
  const size_t rowb = (size_t)b * SEQ;

  // ---- Q B-fragments (packed u32, pre-scaled by 1/8) ----
  s16x8 qhi[2], qlo[2];
  {
    const unsigned* qp = QHL + (rowb + q0 + c) * DM + h * DH + g * 8;
#pragma unroll
    for (int ds = 0; ds < 2; ++ds) {
      unsigned uw[8];
      *(uint4*)&uw[0] = *(const uint4*)(qp + ds * 32);
      *(uint4*)&uw[4] = *(const uint4*)(qp + ds * 32 + 4);
      union { s16x8 v; unsigned u[4]; } hi_, lo_;
#pragma unroll
      for (int p = 0; p < 4; ++p) {
        hi_.u[p] = (uw[2 * p] & 0xFFFFu) | (uw[2 * p + 1] << 16);
        lo_.u[p] = (uw[2 * p] >> 16) | (uw[2 * p + 1] & 0xFFFF0000u);
      }
      qhi[ds] = hi_.v; qlo[ds] = lo_.v;
    }
  }

  // ---- swapped QK^T: S^T = Khi*Qhi + Klo*Qhi + Khi*Qlo ----
  f32x4 accs[32];
#pragma unroll
  for (int i = 0; i < 32; ++i) accs[i] = (f32x4){0.f, 0.f, 0.f, 0.f};
  {
    const size_t kcol = (size_t)h * DH + g * 8;
#pragma unroll
    for (int tt = 0; tt < 32; ++tt) {
      const size_t krow = (rowb + w * 512 + tt * 16 + c) * DM + kcol;
      s16x8 kh0 = *(const s16x8*)(Khi + krow);
      s16x8 kh1 = *(const s16x8*)(Khi + krow + 32);
      s16x8 kl0 = *(const s16x8*)(Klo + krow);
      s16x8 kl1 = *(const s16x8*)(Klo + krow + 32);
      accs[tt] = __builtin_amdgcn_mfma_f32_16x16x32_bf16(kh0, qhi[0], accs[tt], 0, 0, 0);
      accs[tt] = __builtin_amdgcn_mfma_f32_16x16x32_bf16(kh1, qhi[1], accs[tt], 0, 0, 0);
      accs[tt] = __builtin_amdgcn_mfma_f32_16x16x32_bf16(kl0, qhi[0], accs[tt], 0, 0, 0);
      accs[tt] = __builtin_amdgcn_mfma_f32_16x16x32_bf16(kl1, qhi[1], accs[tt], 0, 0, 0);
      accs[tt] = __builtin_amdgcn_mfma_f32_16x16x32_bf16(kh0, qlo[0], accs[tt], 0, 0, 0);
      accs[tt] = __builtin_amdgcn_mfma_f32_16x16x32_bf16(kh1, qlo[1], accs[tt], 0, 0, 0);
    }
  }

  // ---- row max (row = c), thread-local + shfl over g + LDS over waves ----
  float vm;
  {
    float m = accs[0][0];
#pragma unroll
    for (int tt = 0; tt < 32; ++tt)
#pragma unroll
      for (int r = 0; r < 4; ++r) m = fmaxf(m, accs[tt][r]);
    m = fmaxf(m, __shfl_xor(m, 16));
    m = fmaxf(m, __shfl_xor(m, 32));
    if (lane < 16) smax[c][w] = m;
    __syncthreads();
    float4 m4 = *(float4*)&smax[c][0];
    vm = fmaxf(fmaxf(m4.x, m4.y), fmaxf(m4.z, m4.w));
  }

  // ---- threshold: 14-iter float bisection on [vmax-4, vmax] ----
  float blo = vm - 4.0f, bhi = vm;
#pragma unroll 1
  for (int it = 0; it < 14; ++it) {
    const int par = it & 1;
    const float mid = 0.5f * (blo + bhi);
    int cnt = 0;
#pragma unroll
    for (int tt = 0; tt < 32; ++tt)
#pragma unroll
      for (int r = 0; r < 4; ++r) cnt += (accs[tt][r] >= mid) ? 1 : 0;
    cnt += __shfl_xor(cnt, 16);
    cnt += __shfl_xor(cnt, 32);
    if (lane < 16) scnt[par][c][w] = (unsigned)cnt;
    __syncthreads();
    uint4 cc = *(uint4*)&scnt[par][c][0];
    int tot = (int)(cc.x + cc.y + cc.z + cc.w);
    bool ge = tot >= TOPKN;
    blo = ge ? mid : blo;
    bhi = ge ? bhi : mid;
  }

  // ---- exp in-place + Z ----
  float rinv;
  {
    const float L2E = 1.44269504f;
    const float mh = vm * L2E;
    float z = 0.f;
#pragma unroll
    for (int tt = 0; tt < 32; ++tt)
#pragma unroll
      for (int r = 0; r < 4; ++r) {
        float s = accs[tt][r];
        float e = (s >= blo) ? exp2f(fmaf(s, L2E, -mh)) : 0.f;
        z += e;
        accs[tt][r] = e;
      }
    z += __shfl_xor(z, 16);
    z += __shfl_xor(z, 32);
    if (lane < 16) szum[c][w] = z;
    __syncthreads();
    float4 z4 = *(float4*)&szum[c][0];
    rinv = 1.f / (z4.x + z4.y + z4.z + z4.w);
  }

  // ---- PV: 16x16x16 MFMA, P from registers (B), V^T from global (A) ----
  // kt loop FULLY unrolled: accs indices must stay compile-time constants.
  f32x4 opv[4];
#pragma unroll
  for (int j = 0; j < 4; ++j) opv[j] = (f32x4){0.f, 0.f, 0.f, 0.f};
  {
    const unsigned short* vb0 = Vt + ((size_t)bh * DH + c) * SEQ + w * 512 + g * 4;
#pragma unroll
    for (int kt = 0; kt < 32; ++kt) {
      union { s16x4 v; unsigned u[2]; } pb;
      pb.u[0] = (unsigned)f2bf(accs[kt][0]) | ((unsigned)f2bf(accs[kt][1]) << 16);
      pb.u[1] = (unsigned)f2bf(accs[kt][2]) | ((unsigned)f2bf(accs[kt][3]) << 16);
#pragma unroll
      for (int j = 0; j < 4; ++j) {
        s16x4 va = *(const s16x4*)(vb0 + (size_t)j * 16 * SEQ + kt * 16);
        MFMA1616(opv[j], va, pb.v);
      }
    }
    MFMA1616_FENCE();
  }

  // ---- cross-wave reduce + scale + packed store ----
#pragma unroll
  for (int j = 0; j < 4; ++j)
    *(f32x4*)&ctxp[w][c][j * 16 + g * 4] = opv[j];
  __syncthreads();
  {
    f32x4 s0 = *(const f32x4*)&ctxp[0][c][w * 16 + g * 4];
    f32x4 s1 = *(const f32x4*)&ctxp[1][c][w * 16 + g * 4];
    f32x4 s2 = *(const f32x4*)&ctxp[2][c][w * 16 + g * 4];
    f32x4 s3 = *(const f32x4*)&ctxp[3][c][w * 16 + g * 4];
    f32x4 ssum = (s0 + s1) + (s2 + s3);
    unsigned ov[4];
    ov[0] = packHL(ssum[0] * rinv);
    ov[1] = packHL(ssum[1] * rinv);
    ov[2] = packHL(ssum[2] * rinv);
    ov[3] = packHL(ssum[3] * rinv);
    *(uint4*)&CtxP[(rowb + q0 + c) * DM + h * DH + w * 16 + g * 4] = *(uint4*)&ov[0];
  }
}

extern "C" void kernel_launch(void* const* d_in, const int* in_sizes, int n_in,
                              void* d_out, int out_size, void* d_ws, size_t ws_size,
                              hipStream_t stream) {
  const float* q  = (const float*)d_in[0];
  const float* k  = (const float*)d_in[1];
  const float* v  = (const float*)d_in[2];
  const float* Wq = (const float*)d_in[3];
  const float* bq = (const float*)d_in[4];
  const float* Wk = (const float*)d_in[5];
  const float* bk = (const float*)d_in[6];
  const float* Wv = (const float*)d_in[7];
  const float* bv = (const float*)d_in[8];
  const float* Wo = (const float*)d_in[9];
  const float* bo = (const float*)d_in[10];
  float* out = (float*)d_out;

  char* ws = (char*)d_ws;
  unsigned* QHL       = (unsigned*)ws;                        // 16 MiB (packed hi|lo)
  unsigned short* Khi = (unsigned short*)(ws + (16u << 20));  // 8 MiB
  unsigned short* Klo = (unsigned short*)(ws + (24u << 20));  // 8 MiB
  unsigned short* Vt  = (unsigned short*)(ws + (32u << 20));  // 8 MiB
  unsigned short* Whi = (unsigned short*)(ws + (40u << 20));  // 2 MiB (reused)
  unsigned short* Wlo = (unsigned short*)(ws + (42u << 20));  // 2 MiB (reused)

  convW<<<1024, 256, 0, stream>>>(Wq, Whi, Wlo);
  gemm_mfma<0, 1><<<512, 256, 0, stream>>>(q, Whi, Wlo, bq, QHL, nullptr);
  convW<<<1024, 256, 0, stream>>>(Wk, Whi, Wlo);
  gemm_mfma<0, 2><<<512, 256, 0, stream>>>(k, Whi, Wlo, bk, Khi, Klo);
  convW<<<1024, 256, 0, stream>>>(Wv, Whi, Wlo);
  gemm_mfma<0, 3><<<512, 256, 0, stream>>>(v, Whi, Wlo, bv, Vt, nullptr);
  attn_mfma<<<BATCH * NH * (SEQ / 16), 256, 0, stream>>>(QHL, Khi, Klo, Vt, QHL);
  convW<<<1024, 256, 0, stream>>>(Wo, Whi, Wlo);
  gemm_mfma<1, 0><<<512, 256, 0, stream>>>(QHL, Whi, Wlo, bo, out, nullptr);
}